// Round 7
// baseline (558.757 us; speedup 1.0000x reference)
//
#include <hip/hip_runtime.h>
#include <hip/hip_bf16.h>

#define NE   8
#define DIN  2048
#define DOUT 8192
#define NTOK 8192

typedef __bf16 bf16;
typedef __attribute__((ext_vector_type(8))) __bf16 bf16x8;
typedef __attribute__((ext_vector_type(4))) float f32x4;

__device__ __forceinline__ bf16 f2bf(float x) {
  union { float f; unsigned u; } v; v.f = x;
  unsigned r = v.u + 0x7fffu + ((v.u >> 16) & 1u);
  union { unsigned short s; bf16 b; } o; o.s = (unsigned short)(r >> 16);
  return o.b;
}

// ---------------- pass 1a: A fp32 -> bf16 ----------------
__global__ __launch_bounds__(256) void convertA(const float* __restrict__ A,
                                                bf16* __restrict__ Ab) {
  size_t i = ((size_t)blockIdx.x * 256 + threadIdx.x) * 8;
  float4 a = *(const float4*)(A + i);
  float4 b = *(const float4*)(A + i + 4);
  const float* f = (const float*)&a;
  const float* g = (const float*)&b;
  bf16x8 v;
  #pragma unroll
  for (int j = 0; j < 4; ++j) { v[j] = f2bf(f[j]); v[4 + j] = f2bf(g[j]); }
  *(bf16x8*)(Ab + i) = v;
}

// ------- pass 1b: W [E][K][N] fp32 -> BT [E][N][K] bf16 (transpose) -------
__global__ __launch_bounds__(256) void convertB(const float* __restrict__ W,
                                                bf16* __restrict__ BT) {
  __shared__ bf16 tile[64][66];
  const int e  = blockIdx.z;
  const int n0 = blockIdx.x * 64;
  const int k0 = blockIdx.y * 64;
  const int t  = threadIdx.x;
  const int tr = t >> 2;
  const int tc = (t & 3) << 4;

  const float* src = W + ((size_t)e * DIN + k0 + tr) * DOUT + n0 + tc;
  #pragma unroll
  for (int i = 0; i < 4; ++i) {
    float4 v = *(const float4*)(src + 4 * i);
    const float* f = (const float*)&v;
    #pragma unroll
    for (int j = 0; j < 4; ++j) tile[tr][tc + 4 * i + j] = f2bf(f[j]);
  }
  __syncthreads();

  bf16x8 v0, v1;
  #pragma unroll
  for (int j = 0; j < 8; ++j) { v0[j] = tile[tc + j][tr]; v1[j] = tile[tc + 8 + j][tr]; }
  bf16* dst = BT + ((size_t)e * DOUT + n0 + tr) * DIN + k0 + tc;
  *(bf16x8*)dst = v0;
  *(bf16x8*)(dst + 8) = v1;
}

// ---------- pass 2: grouped GEMM, 256x256, m201 8-phase schedule ----------
// C[m][n] = sum_k A[m][k] * BT[e][n][k]. BK=64 split as 2 kk-halves of 32.
// LDS: A[2 dbuf][2 half][256r x 32k] + B same = 128 KiB. Tile T -> dbuf T&1.
// Iteration computes tiles T (phases 1-4) and T+1 (phases 5-8); each phase
// stages ONE half-tile (2 x GL16) per the ledger:
//  p1:A(T+1,k1) p2:B(T+2,k0) p3:A(T+2,k0) p4:B(T+2,k1)+vmcnt(6)
//  p5:A(T+2,k1) p6:B(T+3,k0) p7:A(T+3,k0) p8:B(T+3,k1)+vmcnt(6)
// Every half lands >=1 gate before first read; every stage targets a slot
// whose last ds_read was in an earlier phase (cross-wave GL hazard safe).
// Swizzle: 16B-granule g' = g ^ ((row>>1)&3); linear GL dest + pre-swizzled
// global source (rule 21); b128 reads hit the 8-lanes/slot floor (no conflict).

#define GLB(gp, lp) __builtin_amdgcn_global_load_lds(                        \
    (const __attribute__((address_space(1))) void*)(gp),                     \
    (__attribute__((address_space(3))) void*)(lp), 16, 0, 0)

__global__ __launch_bounds__(512, 2) void grouped_gemm(
    const bf16* __restrict__ A, const bf16* __restrict__ BT,
    const void* __restrict__ es, float* __restrict__ C) {
  __shared__ __attribute__((aligned(128))) char smem[131072];

  // XCD L2-coop: XCD c owns ntiles [4c,4c+4) x all 32 mtiles, ntile-fastest
  const int bid   = blockIdx.x;
  const int c     = bid & 7;
  const int local = bid >> 3;            // 0..127
  const int mtile = local >> 2;          // 0..31
  const int ntile = c * 4 + (local & 3); // 0..31
  const int mrow  = mtile * 256;
  const int ncol  = ntile * 256;

  // expert offsets (int32 or int64 input)
  const int* p32 = (const int*)es;
  const long long* p64 = (const long long*)es;
  const bool is64 = (p32[1] == 0);
  int offs[NE + 1];
  offs[0] = 0;
  #pragma unroll
  for (int i = 0; i < NE; ++i)
    offs[i + 1] = offs[i] + (int)(is64 ? p64[i] : (long long)p32[i]);
  int e0 = 0, e1 = 0;
  #pragma unroll
  for (int i = 0; i < NE; ++i) {
    if (mrow >= offs[i + 1]) e0 = i + 1;
    if (mrow + 255 >= offs[i + 1]) e1 = i + 1;
  }

  const int t    = threadIdx.x;
  const int lane = t & 63;
  const int w    = t >> 6;
  const int wm   = w >> 2;             // 0/1: rows wm*128
  const int wn   = w & 3;              // 0..3: cols wn*64
  const int l15  = lane & 15;
  const int kg   = lane >> 4;          // 0..3

  const int rg16 = (kg ^ ((l15 >> 1) & 3)) << 4;   // swizzled read granule (bytes)
  const int arow = (wm * 128 + l15) * 64;          // A row-byte base in half
  const int brow = (wn * 64 + l15) * 64;           // B row-byte base in half
  const int t16  = t * 16;
  const int ssrc = (((t & 3) ^ ((t >> 3) & 3)) << 3);  // pre-swizzled src col (elems)

  const bf16* Agb = A + (size_t)(mrow + (t >> 2)) * DIN + ssrc;
  float* Cb = C + (size_t)mrow * DOUT + ncol;

#define AH(d, h) (smem + (((d) * 2 + (h)) << 14))
#define BH(d, h) (smem + 65536 + (((d) * 2 + (h)) << 14))
#define LDA_(d, kk, mf) (*(const bf16x8*)(AH(d, kk) + arow + ((mf) << 10) + rg16))
#define LDB_(d, kk, nf) (*(const bf16x8*)(BH(d, kk) + brow + ((nf) << 10) + rg16))

#define STA(tile, h) do {                                                    \
    const bf16* g_ = Agb + (size_t)(tile) * 64 + (h) * 32;                   \
    char* l_ = AH((tile) & 1, h) + t16;                                      \
    GLB(g_, l_); GLB(g_ + (size_t)128 * DIN, l_ + 8192); } while (0)
#define STB(tile, h) do {                                                    \
    const bf16* g_ = Bgb + (size_t)(tile) * 64 + (h) * 32;                   \
    char* l_ = BH((tile) & 1, h) + t16;                                      \
    GLB(g_, l_); GLB(g_ + (size_t)128 * DIN, l_ + 8192); } while (0)

#define GATE6 asm volatile("s_waitcnt vmcnt(6)" ::: "memory")
#define GATE0 asm volatile("s_waitcnt vmcnt(0)" ::: "memory")
#define NOST  (void)0

#define PHASE(d, kk, mh, STMT, GATE) do {                                    \
    if ((mh) == 0) {                                                         \
      bF[0] = LDB_(d, kk, 0); bF[1] = LDB_(d, kk, 1);                        \
      bF[2] = LDB_(d, kk, 2); bF[3] = LDB_(d, kk, 3);                        \
    }                                                                        \
    bf16x8 aF[4];                                                            \
    aF[0] = LDA_(d, kk, (mh) * 4 + 0); aF[1] = LDA_(d, kk, (mh) * 4 + 1);    \
    aF[2] = LDA_(d, kk, (mh) * 4 + 2); aF[3] = LDA_(d, kk, (mh) * 4 + 3);    \
    STMT;                                                                    \
    __builtin_amdgcn_s_barrier();                                            \
    asm volatile("s_waitcnt lgkmcnt(0)" ::: "memory");                       \
    __builtin_amdgcn_sched_barrier(0);                                       \
    __builtin_amdgcn_s_setprio(1);                                           \
    _Pragma("unroll")                                                        \
    for (int m4_ = 0; m4_ < 4; ++m4_)                                        \
      _Pragma("unroll")                                                      \
      for (int nf_ = 0; nf_ < 4; ++nf_)                                      \
        acc[(mh) * 4 + m4_][nf_] = __builtin_amdgcn_mfma_f32_16x16x32_bf16(  \
            aF[m4_], bF[nf_], acc[(mh) * 4 + m4_][nf_], 0, 0, 0);            \
    __builtin_amdgcn_s_setprio(0);                                           \
    GATE;                                                                    \
    __builtin_amdgcn_s_barrier();                                            \
  } while (0)

  for (int e = e0; e <= e1; ++e) {
    const bf16* Bgb = BT + ((size_t)e * DOUT + ncol + (t >> 2)) * DIN + ssrc;

    f32x4 acc[8][4];
    #pragma unroll
    for (int m = 0; m < 8; ++m)
      #pragma unroll
      for (int n = 0; n < 4; ++n) acc[m][n] = (f32x4){0.f, 0.f, 0.f, 0.f};
    bf16x8 bF[4];

    // prologue: 7 halves (tiles 0 full, tile 1 minus A-kk1), then gate
    STB(0, 0); STA(0, 0); STB(0, 1); STA(0, 1);
    STB(1, 0); STA(1, 0); STB(1, 1);
    asm volatile("s_waitcnt vmcnt(6)" ::: "memory");  // tile 0 fully landed
    __builtin_amdgcn_s_barrier();

    // main: iterations 0..14, tiles T=2it, T+1; stage T+1..T+3 per ledger
    for (int it = 0; it < 15; ++it) {
      const int T = 2 * it;
      PHASE(0, 0, 0, STA(T + 1, 1), NOST);
      PHASE(0, 0, 1, STB(T + 2, 0), NOST);
      PHASE(0, 1, 0, STA(T + 2, 0), NOST);
      PHASE(0, 1, 1, STB(T + 2, 1), GATE6);
      PHASE(1, 0, 0, STA(T + 2, 1), NOST);
      PHASE(1, 0, 1, STB(T + 3, 0), NOST);
      PHASE(1, 1, 0, STA(T + 3, 0), NOST);
      PHASE(1, 1, 1, STB(T + 3, 1), GATE6);
    }
    // final iteration: T=30,31; only A(31,k1) left to stage; drain at p4
    PHASE(0, 0, 0, STA(31, 1), NOST);
    PHASE(0, 0, 1, NOST, NOST);
    PHASE(0, 1, 0, NOST, NOST);
    PHASE(0, 1, 1, NOST, GATE0);
    PHASE(1, 0, 0, NOST, NOST);
    PHASE(1, 0, 1, NOST, NOST);
    PHASE(1, 1, 0, NOST, NOST);
    PHASE(1, 1, 1, NOST, NOST);

    // epilogue: masked C-write (mask matters only for the split mtile 27)
    int rlo = offs[e] - mrow;     if (rlo < 0)   rlo = 0;
    int rhi = offs[e + 1] - mrow; if (rhi > 256) rhi = 256;
    #pragma unroll
    for (int mf = 0; mf < 8; ++mf) {
      const int rb = wm * 128 + mf * 16 + kg * 4;
      #pragma unroll
      for (int j = 0; j < 4; ++j) {
        const int r = rb + j;
        if (r >= rlo && r < rhi) {
          #pragma unroll
          for (int nf = 0; nf < 4; ++nf)
            Cb[(size_t)r * DOUT + wn * 64 + nf * 16 + l15] = acc[mf][nf][j];
        }
      }
    }
  }
#undef PHASE
#undef STA
#undef STB
}

// ---------------- fallback (ws too small): fp32 tiled GEMM ----------------
__device__ __forceinline__ int find_expert_fb(const void* esv, int mrow) {
  const int* p32 = (const int*)esv;
  const long long* p64 = (const long long*)esv;
  bool is64 = (p32[1] == 0);
  long long cum = 0; int e = 0;
  #pragma unroll
  for (int i = 0; i < NE; ++i) {
    long long s = is64 ? p64[i] : (long long)p32[i];
    long long nx = cum + s;
    if ((long long)mrow >= nx) e = i + 1;
    cum = nx;
  }
  return e;
}

__global__ __launch_bounds__(256) void fallback_gemm(
    const float* __restrict__ A, const float* __restrict__ W,
    const void* __restrict__ es, float* __restrict__ C) {
  __shared__ float Asf[64][17];
  __shared__ float Bsf[16][65];
  const int bid = blockIdx.x;
  const int mtile = bid >> 7;
  const int ntile = bid & 127;
  const int mrow = mtile * 64, ncol = ntile * 64;
  const int e = find_expert_fb(es, mrow);
  const int t = threadIdx.x;
  const int tx = t & 15, ty = t >> 4;
  float acc[4][4] = {};
  const float* Ab = A + (size_t)mrow * DIN;
  const float* Wb = W + (size_t)e * DIN * DOUT + ncol;
  for (int kb = 0; kb < DIN; kb += 16) {
    {
      const int r = t >> 2, cc = (t & 3) * 4;
      float4 v = *(const float4*)(Ab + (size_t)r * DIN + kb + cc);
      const float* f = (const float*)&v;
      #pragma unroll
      for (int j = 0; j < 4; ++j) Asf[r][cc + j] = f[j];
      const int r2 = t >> 4, c2 = (t & 15) * 4;
      float4 wv = *(const float4*)(Wb + (size_t)(kb + r2) * DOUT + c2);
      const float* g = (const float*)&wv;
      #pragma unroll
      for (int j = 0; j < 4; ++j) Bsf[r2][c2 + j] = g[j];
    }
    __syncthreads();
    #pragma unroll
    for (int k = 0; k < 16; ++k)
      #pragma unroll
      for (int i = 0; i < 4; ++i)
        #pragma unroll
        for (int j = 0; j < 4; ++j)
          acc[i][j] += Asf[ty * 4 + i][k] * Bsf[k][tx * 4 + j];
    __syncthreads();
  }
  #pragma unroll
  for (int i = 0; i < 4; ++i)
    #pragma unroll
    for (int j = 0; j < 4; ++j)
      C[(size_t)(mrow + ty * 4 + i) * DOUT + ncol + tx * 4 + j] = acc[i][j];
}

extern "C" void kernel_launch(void* const* d_in, const int* in_sizes, int n_in,
                              void* d_out, int out_size, void* d_ws, size_t ws_size,
                              hipStream_t stream) {
  const float* A = (const float*)d_in[0];
  const float* W = (const float*)d_in[1];
  const void*  es = (const void*)d_in[2];
  float* C = (float*)d_out;

  const size_t needA = (size_t)NTOK * DIN * sizeof(bf16);        // 32 MB
  const size_t needB = (size_t)NE * DIN * DOUT * sizeof(bf16);   // 256 MB

  if (ws_size >= needA + needB) {
    bf16* Ab = (bf16*)d_ws;
    bf16* BT = (bf16*)((char*)d_ws + needA);
    convertA<<<(NTOK * DIN) / (256 * 8), 256, 0, stream>>>(A, Ab);
    dim3 gB(DOUT / 64, DIN / 64, NE);
    convertB<<<gB, 256, 0, stream>>>(W, BT);
    grouped_gemm<<<(NTOK / 256) * (DOUT / 256), 512, 0, stream>>>(Ab, BT, es, C);
  } else {
    fallback_gemm<<<(NTOK / 64) * (DOUT / 64), 256, 0, stream>>>(A, W, es, C);
  }
}

// Round 8
// 537.725 us; speedup vs baseline: 1.0391x; 1.0391x over previous
//
#include <hip/hip_runtime.h>
#include <hip/hip_bf16.h>

#define NE   8
#define DIN  2048
#define DOUT 8192
#define NTOK 8192

typedef __bf16 bf16;
typedef __attribute__((ext_vector_type(8))) __bf16 bf16x8;
typedef __attribute__((ext_vector_type(4))) float f32x4;

// round-to-nearest-even f32 -> bf16 (finite inputs)
__device__ __forceinline__ bf16 f2bf(float x) {
  union { float f; unsigned u; } v; v.f = x;
  unsigned r = v.u + 0x7fffu + ((v.u >> 16) & 1u);
  union { unsigned short s; bf16 b; } o; o.s = (unsigned short)(r >> 16);
  return o.b;
}

__device__ __forceinline__ int find_expert(const void* esv, int mrow) {
  const int* p32 = (const int*)esv;
  const long long* p64 = (const long long*)esv;
  bool is64 = (p32[1] == 0);
  long long cum = 0; int e = 0;
  #pragma unroll
  for (int i = 0; i < NE; ++i) {
    long long s = is64 ? p64[i] : (long long)p32[i];
    long long nx = cum + s;
    if ((long long)mrow >= nx) e = i + 1;
    cum = nx;
  }
  return e;
}

// ---------------- pass 1a: A fp32 -> bf16 (same layout) ----------------
__global__ __launch_bounds__(256) void convertA(const float* __restrict__ A,
                                                bf16* __restrict__ Ab) {
  size_t i = ((size_t)blockIdx.x * 256 + threadIdx.x) * 8;
  float4 a = *(const float4*)(A + i);
  float4 b = *(const float4*)(A + i + 4);
  const float* f = (const float*)&a;
  const float* g = (const float*)&b;
  bf16x8 v;
  #pragma unroll
  for (int j = 0; j < 4; ++j) { v[j] = f2bf(f[j]); v[4 + j] = f2bf(g[j]); }
  *(bf16x8*)(Ab + i) = v;
}

// ------ pass 2: grouped GEMM with FUSED W fp32->bf16 transpose staging ------
// C[m][n] = sum_k A[m][k] * W[e][k][n].  128x128 tile, BK=64, 4 waves,
// 32 KiB LDS (multi-block/CU -> implicit cross-block overlap, m114).
// A-path: gload_lds, swizzle f_A(row)=row&7 (r5/r6-verified, conflicts=0).
// B-path (new): reg-staged from W fp32 [k][n]: thread (tn=t&31, tk=t>>5)
// loads 8 float4 of rows kb+8tk..+8, casts to bf16 (cvt_pk), writes 4
// transposed ds_write_b128 into Bs[n][k] at slot tk ^ f_B(row),
// f_B(row) = (row&7)^((row>>3)&7).  Both the 4tn-strided writes and the
// 16-consecutive-row frag reads hit exactly 2 lanes/slot per quarter-wave
// (conflict-free).  Dispatch mtile-fastest: XCD's concurrent blocks share
// W k-strips (L2); A re-reads served by L3 (32 MB total).
#define BM 128
#define BN 128
#define BK 64

#define GL(gp, lp) __builtin_amdgcn_global_load_lds(                        \
    (const __attribute__((address_space(1))) void*)(gp),                    \
    (__attribute__((address_space(3))) void*)(lp), 16, 0, 0)

__global__ __launch_bounds__(256) void grouped_gemm(
    const bf16* __restrict__ A, const float* __restrict__ W,
    const void* __restrict__ es, float* __restrict__ C) {
  __shared__ bf16 As[BM * BK];
  __shared__ bf16 Bs[BN * BK];

  // XCD dispatch: XCD c owns ntiles [8c,8c+8) x all 64 mtiles, mtile-fastest
  const int bid   = blockIdx.x;
  const int c     = bid & 7;
  const int local = bid >> 3;             // 0..511
  const int mtile = local & 63;           // fastest: concurrent blocks share W strips
  const int ntile = c * 8 + (local >> 6); // 0..63
  const int mrow  = mtile * BM;
  const int ncol  = ntile * BN;
  const int e     = find_expert(es, mrow);

  const int t    = threadIdx.x;
  const int lane = t & 63;
  const int wr   = ((t >> 6) >> 1) * 64;   // wave rows: 0/64
  const int wc   = ((t >> 6) & 1) * 64;    // wave cols: 0/64
  const int l15  = lane & 15;
  const int kg   = lane >> 4;              // 0..3

  // A staging: linear LDS dest (t*16B), pre-swizzled global source col
  const int srow = t >> 3;                              // 0..31
  const int ssrc = ((t & 7) ^ (srow & 7)) * 8;          // elems
  const int sdst = t * 8;                               // elems per 32-row chunk
  const bf16* Ag = A + (size_t)(mrow + srow) * DIN + ssrc;

  // B staging: thread covers n0=4*(t&31), k0=8*(t>>5)
  const int tn4 = (t & 31) * 4;
  const int tk  = t >> 5;
  const float* Wg = W + (size_t)e * DIN * DOUT + (size_t)(tk * 8) * DOUT + ncol + tn4;
  char* BsB = (char*)Bs;

  f32x4 acc[4][4];
  #pragma unroll
  for (int m = 0; m < 4; ++m)
    #pragma unroll
    for (int n = 0; n < 4; ++n) acc[m][n] = (f32x4){0.f, 0.f, 0.f, 0.f};

  for (int kt = 0; kt < DIN / BK; ++kt) {
    const int kb = kt * BK;

    // ---- B global loads (fp32, coalesced 512B runs per k-row)
    float4 wv0 = *(const float4*)(Wg + (size_t)(kb + 0) * DOUT);
    float4 wv1 = *(const float4*)(Wg + (size_t)(kb + 1) * DOUT);
    float4 wv2 = *(const float4*)(Wg + (size_t)(kb + 2) * DOUT);
    float4 wv3 = *(const float4*)(Wg + (size_t)(kb + 3) * DOUT);
    float4 wv4 = *(const float4*)(Wg + (size_t)(kb + 4) * DOUT);
    float4 wv5 = *(const float4*)(Wg + (size_t)(kb + 5) * DOUT);
    float4 wv6 = *(const float4*)(Wg + (size_t)(kb + 6) * DOUT);
    float4 wv7 = *(const float4*)(Wg + (size_t)(kb + 7) * DOUT);

    // ---- A stage via global_load_lds (f_A pre-swizzled source)
    #pragma unroll
    for (int i = 0; i < 4; ++i)
      GL(Ag + (size_t)(i * 32) * DIN + kb, As + i * 2048 + sdst);

    // ---- B convert + transposed swizzled LDS writes
    #pragma unroll
    for (int i = 0; i < 4; ++i) {
      bf16x8 bv;
      bv[0] = (bf16)(((const float*)&wv0)[i]);
      bv[1] = (bf16)(((const float*)&wv1)[i]);
      bv[2] = (bf16)(((const float*)&wv2)[i]);
      bv[3] = (bf16)(((const float*)&wv3)[i]);
      bv[4] = (bf16)(((const float*)&wv4)[i]);
      bv[5] = (bf16)(((const float*)&wv5)[i]);
      bv[6] = (bf16)(((const float*)&wv6)[i]);
      bv[7] = (bf16)(((const float*)&wv7)[i]);
      const int row  = tn4 + i;
      const int slot = tk ^ ((row & 7) ^ ((row >> 3) & 7));
      *(bf16x8*)(BsB + row * 128 + slot * 16) = bv;
    }

    __syncthreads();   // drains vmcnt (A gloads) + lgkmcnt (B writes)

    #pragma unroll
    for (int kk = 0; kk < 2; ++kk) {
      const int rcA = ((kk * 4 + kg) ^ (l15 & 7)) * 8;   // elems
      bf16x8 af[4], bfr[4];
      #pragma unroll
      for (int m = 0; m < 4; ++m)
        af[m] = *(const bf16x8*)&As[(wr + m * 16 + l15) * BK + rcA];
      #pragma unroll
      for (int n = 0; n < 4; ++n) {
        const int row = wc + n * 16 + l15;
        const int g   = (kk * 4 + kg) ^ (l15 & 7) ^
                        (((wc >> 3) + 2 * n + (l15 >> 3)) & 7);
        bfr[n] = *(const bf16x8*)(BsB + row * 128 + g * 16);
      }
      #pragma unroll
      for (int m = 0; m < 4; ++m)
        #pragma unroll
        for (int n = 0; n < 4; ++n)
          acc[m][n] = __builtin_amdgcn_mfma_f32_16x16x32_bf16(
              af[m], bfr[n], acc[m][n], 0, 0, 0);
    }
    __syncthreads();
  }

  // C/D layout: col = lane&15, row = (lane>>4)*4 + reg
  float* Cb = C + (size_t)mrow * DOUT + ncol;
  const int r0 = wr + kg * 4;
  const int c0 = wc + l15;
  #pragma unroll
  for (int m = 0; m < 4; ++m)
    #pragma unroll
    for (int j = 0; j < 4; ++j)
      #pragma unroll
      for (int n = 0; n < 4; ++n)
        Cb[(size_t)(r0 + m * 16 + j) * DOUT + c0 + n * 16] = acc[m][n][j];
}

// ---------------- fallback (ws too small): fp32 tiled GEMM ----------------
__global__ __launch_bounds__(256) void fallback_gemm(
    const float* __restrict__ A, const float* __restrict__ W,
    const void* __restrict__ es, float* __restrict__ C) {
  __shared__ float Asf[64][17];
  __shared__ float Bsf[16][65];
  const int bid = blockIdx.x;
  const int mtile = bid >> 7;
  const int ntile = bid & 127;
  const int mrow = mtile * 64, ncol = ntile * 64;
  const int e = find_expert(es, mrow);
  const int t = threadIdx.x;
  const int tx = t & 15, ty = t >> 4;
  float acc[4][4] = {};
  const float* Ab = A + (size_t)mrow * DIN;
  const float* Wb = W + (size_t)e * DIN * DOUT + ncol;
  for (int kb = 0; kb < DIN; kb += 16) {
    {
      const int r = t >> 2, cc = (t & 3) * 4;
      float4 v = *(const float4*)(Ab + (size_t)r * DIN + kb + cc);
      const float* f = (const float*)&v;
      #pragma unroll
      for (int j = 0; j < 4; ++j) Asf[r][cc + j] = f[j];
      const int r2 = t >> 4, c2 = (t & 15) * 4;
      float4 wv = *(const float4*)(Wb + (size_t)(kb + r2) * DOUT + c2);
      const float* g = (const float*)&wv;
      #pragma unroll
      for (int j = 0; j < 4; ++j) Bsf[r2][c2 + j] = g[j];
    }
    __syncthreads();
    #pragma unroll
    for (int k = 0; k < 16; ++k)
      #pragma unroll
      for (int i = 0; i < 4; ++i)
        #pragma unroll
        for (int j = 0; j < 4; ++j)
          acc[i][j] += Asf[ty * 4 + i][k] * Bsf[k][tx * 4 + j];
    __syncthreads();
  }
  #pragma unroll
  for (int i = 0; i < 4; ++i)
    #pragma unroll
    for (int j = 0; j < 4; ++j)
      C[(size_t)(mrow + ty * 4 + i) * DOUT + ncol + tx * 4 + j] = acc[i][j];
}

extern "C" void kernel_launch(void* const* d_in, const int* in_sizes, int n_in,
                              void* d_out, int out_size, void* d_ws, size_t ws_size,
                              hipStream_t stream) {
  const float* A = (const float*)d_in[0];
  const float* W = (const float*)d_in[1];
  const void*  es = (const void*)d_in[2];
  float* C = (float*)d_out;

  const size_t needA = (size_t)NTOK * DIN * sizeof(bf16);   // 32 MB

  if (ws_size >= needA) {
    bf16* Ab = (bf16*)d_ws;
    convertA<<<(NTOK * DIN) / (256 * 8), 256, 0, stream>>>(A, Ab);
    grouped_gemm<<<(NTOK / BM) * (DOUT / BN), 256, 0, stream>>>(Ab, W, es, C);
  } else {
    fallback_gemm<<<(NTOK / 64) * (DOUT / 64), 256, 0, stream>>>(A, W, es, C);
  }
}

// Round 9
// 477.336 us; speedup vs baseline: 1.1706x; 1.1265x over previous
//
#include <hip/hip_runtime.h>
#include <hip/hip_bf16.h>

#define NE   8
#define DIN  2048
#define DOUT 8192
#define NTOK 8192

typedef __bf16 bf16;
typedef __attribute__((ext_vector_type(8))) __bf16 bf16x8;
typedef __attribute__((ext_vector_type(16))) float f32x16;

// round-to-nearest-even f32 -> bf16 (finite inputs)
__device__ __forceinline__ bf16 f2bf(float x) {
  union { float f; unsigned u; } v; v.f = x;
  unsigned r = v.u + 0x7fffu + ((v.u >> 16) & 1u);
  union { unsigned short s; bf16 b; } o; o.s = (unsigned short)(r >> 16);
  return o.b;
}

__device__ __forceinline__ int find_expert(const void* esv, int mrow) {
  const int* p32 = (const int*)esv;
  const long long* p64 = (const long long*)esv;
  bool is64 = (p32[1] == 0);
  long long cum = 0; int e = 0;
  #pragma unroll
  for (int i = 0; i < NE; ++i) {
    long long s = is64 ? p64[i] : (long long)p32[i];
    long long nx = cum + s;
    if ((long long)mrow >= nx) e = i + 1;
    cum = nx;
  }
  return e;
}

// ---------------- pass 1a: A fp32 -> bf16 (same layout) ----------------
__global__ __launch_bounds__(256) void convertA(const float* __restrict__ A,
                                                bf16* __restrict__ Ab) {
  size_t i = ((size_t)blockIdx.x * 256 + threadIdx.x) * 8;
  float4 a = *(const float4*)(A + i);
  float4 b = *(const float4*)(A + i + 4);
  const float* f = (const float*)&a;
  const float* g = (const float*)&b;
  bf16x8 v;
  #pragma unroll
  for (int j = 0; j < 4; ++j) { v[j] = f2bf(f[j]); v[4 + j] = f2bf(g[j]); }
  *(bf16x8*)(Ab + i) = v;
}

// ------- pass 1b: W [E][K][N] fp32 -> BT [E][N][K] bf16 (transpose) -------
__global__ __launch_bounds__(256) void convertB(const float* __restrict__ W,
                                                bf16* __restrict__ BT) {
  __shared__ bf16 tile[64][66];
  const int e  = blockIdx.z;
  const int n0 = blockIdx.x * 64;
  const int k0 = blockIdx.y * 64;
  const int t  = threadIdx.x;
  const int tr = t >> 2;
  const int tc = (t & 3) << 4;

  const float* src = W + ((size_t)e * DIN + k0 + tr) * DOUT + n0 + tc;
  #pragma unroll
  for (int i = 0; i < 4; ++i) {
    float4 v = *(const float4*)(src + 4 * i);
    const float* f = (const float*)&v;
    #pragma unroll
    for (int j = 0; j < 4; ++j) tile[tr][tc + 4 * i + j] = f2bf(f[j]);
  }
  __syncthreads();

  bf16x8 v0, v1;
  #pragma unroll
  for (int j = 0; j < 8; ++j) { v0[j] = tile[tc + j][tr]; v1[j] = tile[tc + 8 + j][tr]; }
  bf16* dst = BT + ((size_t)e * DOUT + n0 + tr) * DIN + k0 + tc;
  *(bf16x8*)dst = v0;
  *(bf16x8*)(dst + 8) = v1;
}

// ---- pass 2: grouped GEMM, m97 structure + XOR swizzle + 32x32x16 MFMA ----
// C[m][n] = sum_k A[m][k] * BT[e][n][k]. 128x128 tile, BK=64, 4 waves (2x2),
// each wave 64x64 = 2x2 fragments of 32x32. 32 KiB LDS, multi-block/CU.
// Swizzle (r5/r6-verified, conflicts=0): granule g' = g ^ (row&7), both
// sides; 32x32 frag reads: per 16-lane quarter, 8 slots x 2 lanes = free.
// L2-coop order (r6-verified): XCD c owns ntiles [8c,8c+8) x all mtiles.
// Frag layout 32x32x16: A/B row = lane&31, kgrp = lane>>5 (k = kgrp*8+j);
// C/D col = lane&31, row = (reg&3) + 8*(reg>>2) + 4*(lane>>5)  [m74/m101].
#define BM 128
#define BN 128
#define BK 64

#define GL(gp, lp) __builtin_amdgcn_global_load_lds(                        \
    (const __attribute__((address_space(1))) void*)(gp),                    \
    (__attribute__((address_space(3))) void*)(lp), 16, 0, 0)

__global__ __launch_bounds__(256) void grouped_gemm(
    const bf16* __restrict__ A, const bf16* __restrict__ BT,
    const void* __restrict__ es, float* __restrict__ C) {
  __shared__ bf16 As[BM * BK];
  __shared__ bf16 Bs[BN * BK];

  // XCD ntile-slice dispatch: c = XCD, ntile = c*8 + (local&7), mtile = local>>3
  const int bid   = blockIdx.x;
  const int c     = bid & 7;
  const int local = bid >> 3;            // 0..511
  const int mtile = local >> 3;          // 0..63  (ntile-fastest: share A-panel)
  const int ntile = c * 8 + (local & 7); // 0..63
  const int mrow  = mtile * BM;
  const int ncol  = ntile * BN;
  const int e     = find_expert(es, mrow);

  const int t    = threadIdx.x;
  const int lane = t & 63;
  const int w    = t >> 6;
  const int wr   = (w >> 1) * 64;          // wave rows: 0/64
  const int wc   = (w & 1) * 64;           // wave cols: 0/64
  const int l31  = lane & 31;
  const int l7   = lane & 7;
  const int kgrp = lane >> 5;              // 0/1

  // staging: linear LDS dest (t*16B), pre-swizzled global source col
  const int srow = t >> 3;                              // 0..31
  const int ssrc = ((t & 7) ^ (srow & 7)) * 8;          // elems
  const int sdst = t * 8;                               // elems per 32-row chunk

  const bf16* Ag = A + (size_t)(mrow + srow) * DIN + ssrc;
  const bf16* Bg = BT + ((size_t)e * DOUT + ncol + srow) * DIN + ssrc;

  f32x16 acc[2][2];
  #pragma unroll
  for (int fm = 0; fm < 2; ++fm)
    #pragma unroll
    for (int fn = 0; fn < 2; ++fn)
      #pragma unroll
      for (int r = 0; r < 16; ++r) acc[fm][fn][r] = 0.f;

  for (int kt = 0; kt < DIN / BK; ++kt) {
    const int kb = kt * BK;
    #pragma unroll
    for (int i = 0; i < 4; ++i) {
      GL(Ag + (size_t)(i * 32) * DIN + kb, As + i * 2048 + sdst);
      GL(Bg + (size_t)(i * 32) * DIN + kb, Bs + i * 2048 + sdst);
    }
    __syncthreads();   // compiler drains vmcnt before s_barrier

    #pragma unroll
    for (int ks = 0; ks < 4; ++ks) {
      const int g = ((ks * 2 + kgrp) ^ l7) * 8;   // swizzled granule (elems)
      bf16x8 aF[2], bF[2];
      #pragma unroll
      for (int fm = 0; fm < 2; ++fm)
        aF[fm] = *(const bf16x8*)&As[(wr + fm * 32 + l31) * BK + g];
      #pragma unroll
      for (int fn = 0; fn < 2; ++fn)
        bF[fn] = *(const bf16x8*)&Bs[(wc + fn * 32 + l31) * BK + g];
      #pragma unroll
      for (int fm = 0; fm < 2; ++fm)
        #pragma unroll
        for (int fn = 0; fn < 2; ++fn)
          acc[fm][fn] = __builtin_amdgcn_mfma_f32_32x32x16_bf16(
              aF[fm], bF[fn], acc[fm][fn], 0, 0, 0);
    }
    __syncthreads();
  }

  // C/D layout: col = lane&31, row = (reg&3) + 8*(reg>>2) + 4*(lane>>5)
  float* Cb = C + (size_t)mrow * DOUT + ncol;
  #pragma unroll
  for (int fm = 0; fm < 2; ++fm)
    #pragma unroll
    for (int fn = 0; fn < 2; ++fn)
      #pragma unroll
      for (int r = 0; r < 16; ++r) {
        const int row = wr + fm * 32 + (r & 3) + 8 * (r >> 2) + 4 * kgrp;
        const int col = wc + fn * 32 + l31;
        Cb[(size_t)row * DOUT + col] = acc[fm][fn][r];
      }
}

// ---------------- fallback (ws too small): fp32 tiled GEMM ----------------
__global__ __launch_bounds__(256) void fallback_gemm(
    const float* __restrict__ A, const float* __restrict__ W,
    const void* __restrict__ es, float* __restrict__ C) {
  __shared__ float Asf[64][17];
  __shared__ float Bsf[16][65];
  const int bid = blockIdx.x;
  const int mtile = bid >> 7;
  const int ntile = bid & 127;
  const int mrow = mtile * 64, ncol = ntile * 64;
  const int e = find_expert(es, mrow);
  const int t = threadIdx.x;
  const int tx = t & 15, ty = t >> 4;
  float acc[4][4] = {};
  const float* Ab = A + (size_t)mrow * DIN;
  const float* Wb = W + (size_t)e * DIN * DOUT + ncol;
  for (int kb = 0; kb < DIN; kb += 16) {
    {
      const int r = t >> 2, cc = (t & 3) * 4;
      float4 v = *(const float4*)(Ab + (size_t)r * DIN + kb + cc);
      const float* f = (const float*)&v;
      #pragma unroll
      for (int j = 0; j < 4; ++j) Asf[r][cc + j] = f[j];
      const int r2 = t >> 4, c2 = (t & 15) * 4;
      float4 wv = *(const float4*)(Wb + (size_t)(kb + r2) * DOUT + c2);
      const float* g = (const float*)&wv;
      #pragma unroll
      for (int j = 0; j < 4; ++j) Bsf[r2][c2 + j] = g[j];
    }
    __syncthreads();
    #pragma unroll
    for (int k = 0; k < 16; ++k)
      #pragma unroll
      for (int i = 0; i < 4; ++i)
        #pragma unroll
        for (int j = 0; j < 4; ++j)
          acc[i][j] += Asf[ty * 4 + i][k] * Bsf[k][tx * 4 + j];
    __syncthreads();
  }
  #pragma unroll
  for (int i = 0; i < 4; ++i)
    #pragma unroll
    for (int j = 0; j < 4; ++j)
      C[(size_t)(mrow + ty * 4 + i) * DOUT + ncol + tx * 4 + j] = acc[i][j];
}

extern "C" void kernel_launch(void* const* d_in, const int* in_sizes, int n_in,
                              void* d_out, int out_size, void* d_ws, size_t ws_size,
                              hipStream_t stream) {
  const float* A = (const float*)d_in[0];
  const float* W = (const float*)d_in[1];
  const void*  es = (const void*)d_in[2];
  float* C = (float*)d_out;

  const size_t needA = (size_t)NTOK * DIN * sizeof(bf16);        // 32 MB
  const size_t needB = (size_t)NE * DIN * DOUT * sizeof(bf16);   // 256 MB

  if (ws_size >= needA + needB) {
    bf16* Ab = (bf16*)d_ws;
    bf16* BT = (bf16*)((char*)d_ws + needA);
    convertA<<<(NTOK * DIN) / (256 * 8), 256, 0, stream>>>(A, Ab);
    dim3 gB(DOUT / 64, DIN / 64, NE);
    convertB<<<gB, 256, 0, stream>>>(W, BT);
    grouped_gemm<<<(NTOK / BM) * (DOUT / BN), 256, 0, stream>>>(Ab, BT, es, C);
  } else {
    fallback_gemm<<<(NTOK / 64) * (DOUT / 64), 256, 0, stream>>>(A, W, es, C);
  }
}